// Round 1
// baseline (338.198 us; speedup 1.0000x reference)
//
#include <hip/hip_runtime.h>

#define N1 8192
#define N2 8192
#define DIM 256
#define TILE 128
#define BK 32
#define KITERS (DIM / BK)   // 8

typedef _Float16 half8 __attribute__((ext_vector_type(8)));
typedef _Float16 half4v __attribute__((ext_vector_type(4)));
typedef float f32x4 __attribute__((ext_vector_type(4)));

// Async global->LDS, 16B per lane. LDS dest is wave-uniform base + lane*16.
__device__ __forceinline__ void async_load16(const void* g, void* lds) {
    __builtin_amdgcn_global_load_lds(
        (__attribute__((address_space(1))) void*)g,
        (__attribute__((address_space(3))) void*)lds,
        16, 0, 0);
}

// --- Kernel 1: column mean of x1 (adj pre-zeroed). 512 blocks x 16 rows. ---
__global__ __launch_bounds__(256) void colmean_kernel(const float* __restrict__ x1,
                                                      float* __restrict__ adj) {
    int t = threadIdx.x;                  // dim index 0..255 (coalesced per row)
    size_t r0 = (size_t)blockIdx.x * 16;
    float s = 0.f;
    #pragma unroll
    for (int r = 0; r < 16; ++r) s += x1[(r0 + r) * DIM + t];
    atomicAdd(&adj[t], s * (1.0f / (float)N1));
}

// --- Kernel 2: center/scale/quantize to fp16 + row sq-norms. One wave per row. ---
__global__ __launch_bounds__(256) void quant_kernel(
    const float* __restrict__ x1, const float* __restrict__ x2,
    const float* __restrict__ adj, const float* __restrict__ ls,
    _Float16* __restrict__ y1, _Float16* __restrict__ y2,
    float* __restrict__ sq1, float* __restrict__ sq2) {
    int wave = threadIdx.x >> 6, lane = threadIdx.x & 63;
    int grow = blockIdx.x * 4 + wave;
    const float* x; _Float16* y; float* sq; int row;
    if (grow < N1) { x = x1; y = y1; sq = sq1; row = grow; }
    else           { x = x2; y = y2; sq = sq2; row = grow - N1; }
    int c = lane * 4;
    f32x4 xv = *(const f32x4*)&x[(size_t)row * DIM + c];
    f32x4 av = *(const f32x4*)&adj[c];
    f32x4 lv = *(const f32x4*)&ls[c];
    half4v h;
    float p = 0.f;
    #pragma unroll
    for (int u = 0; u < 4; ++u) {
        float v = (xv[u] - av[u]) / lv[u];
        _Float16 hh = (_Float16)v;
        h[u] = hh;
        float f = (float)hh;
        p += f * f;
    }
    *(half4v*)&y[(size_t)row * DIM + c] = h;
    #pragma unroll
    for (int off = 32; off > 0; off >>= 1) p += __shfl_down(p, off, 64);
    if (lane == 0) sq[row] = p;
}

// --- Kernel 3: 128x128 tile MFMA GEMM, double-buffered LDS, fused Matern epilogue ---
// LDS tiles are row-major [128][32] fp16 (64B rows) with a k-chunk XOR swizzle:
// physical slot s of row r holds global k-chunk s ^ ((r>>1)&3). Dest of
// global_load_lds stays linear (lane-contiguous); the permutation is applied to
// the per-lane GLOBAL source address (rule: both-sides-or-neither). This turns
// the 8-way ds_read_b128 bank conflict of the unswizzled layout into 2-way (free).
// MFMA operands are issued as mfma(b, a) so D has row=N col=M: the 4 acc regs of
// a lane are 4 consecutive N columns -> f32x4 epilogue stores.
__global__ __launch_bounds__(256) void matern_gemm(
    const _Float16* __restrict__ y1, const _Float16* __restrict__ y2,
    const float* __restrict__ sq1, const float* __restrict__ sq2,
    float* __restrict__ out) {
    __shared__ __align__(16) _Float16 As[2][TILE * BK];
    __shared__ __align__(16) _Float16 Bs[2][TILE * BK];

    const int tid  = threadIdx.x;
    const int wave = tid >> 6;
    const int lane = tid & 63;
    const int row0 = blockIdx.x * TILE;  // M offset (x1 rows)
    const int col0 = blockIdx.y * TILE;  // N offset (x2 rows)
    const int wm = (wave >> 1) * 64;     // 2x2 wave grid, 64x64 per wave
    const int wn = (wave & 1) * 64;
    const int fm = lane & 15;            // frag row within 16-row subtile
    const int hq = lane >> 4;            // logical k-chunk (0..3), 8 fp16 each
    // physical slot after swizzle; wm/t*16 are multiples of 16 so row bits 1-2 == fm bits 1-2
    const int sw = hq ^ ((fm >> 1) & 3);

    // staging: 512 16B-chunks per tile, 2 per thread; chunk c -> LDS row c>>2,
    // physical slot c&3 (linear dest). Global source k-chunk is the inverse
    // (== same, XOR is an involution) permutation.
    const int c0 = wave * 128 + lane;
    const int c1 = c0 + 64;
    const int r0c = c0 >> 2, k0c = (((c0 & 3) ^ ((r0c >> 1) & 3))) * 8;
    const int r1c = c1 >> 2, k1c = (((c1 & 3) ^ ((r1c >> 1) & 3))) * 8;
    const int base0 = (wave * 128) * 16;       // wave-uniform LDS byte base
    const int base1 = base0 + 64 * 16;

    f32x4 acc[4][4];
    const f32x4 zero = {0.f, 0.f, 0.f, 0.f};
    #pragma unroll
    for (int i = 0; i < 4; ++i)
        #pragma unroll
        for (int j = 0; j < 4; ++j) acc[i][j] = zero;

    auto stage = [&](int kt, int buf) {
        const int k = kt * BK;
        async_load16(y1 + (size_t)(row0 + r0c) * DIM + k + k0c, (char*)As[buf] + base0);
        async_load16(y1 + (size_t)(row0 + r1c) * DIM + k + k1c, (char*)As[buf] + base1);
        async_load16(y2 + (size_t)(col0 + r0c) * DIM + k + k0c, (char*)Bs[buf] + base0);
        async_load16(y2 + (size_t)(col0 + r1c) * DIM + k + k1c, (char*)Bs[buf] + base1);
    };

    stage(0, 0);
    int cur = 0;
    #pragma unroll
    for (int kt = 0; kt < KITERS; ++kt) {
        // Single barrier per iter: drains vmcnt (tile kt staged, issued one full
        // compute-phase ago) and fences iter kt-1's LDS reads.
        __syncthreads();
        if (kt + 1 < KITERS) stage(kt + 1, cur ^ 1);

        half8 a[4], b[4];
        #pragma unroll
        for (int t = 0; t < 4; ++t)
            a[t] = *(const half8*)&As[cur][(wm + t * 16 + fm) * BK + sw * 8];
        #pragma unroll
        for (int t = 0; t < 4; ++t)
            b[t] = *(const half8*)&Bs[cur][(wn + t * 16 + fm) * BK + sw * 8];
        #pragma unroll
        for (int i = 0; i < 4; ++i)
            #pragma unroll
            for (int j = 0; j < 4; ++j)
                acc[i][j] = __builtin_amdgcn_mfma_f32_16x16x32_f16(b[j], a[i], acc[i][j], 0, 0, 0);
        cur ^= 1;
    }

    // Epilogue: swapped-operand C/D layout: col(lane&15)=M, row((lane>>4)*4+reg)=N.
    const int em = lane & 15;        // M within 16-subtile
    const int en = hq * 4;           // N base within 16-subtile (4 consecutive via reg)
    float s1v[4];
    #pragma unroll
    for (int i = 0; i < 4; ++i)
        s1v[i] = sq1[row0 + wm + i * 16 + em];
    f32x4 s2v[4];
    #pragma unroll
    for (int j = 0; j < 4; ++j)
        s2v[j] = *(const f32x4*)&sq2[col0 + wn + j * 16 + en];

    #pragma unroll
    for (int i = 0; i < 4; ++i) {
        float* rowp = out + (size_t)(row0 + wm + i * 16 + em) * N2 + (col0 + wn + en);
        #pragma unroll
        for (int j = 0; j < 4; ++j) {   // stores use imm offsets j*64B
            f32x4 o;
            #pragma unroll
            for (int r = 0; r < 4; ++r) {
                float d2 = s1v[i] + s2v[j][r] - 2.0f * acc[i][j][r];
                d2 = fmaxf(d2, 0.0f);
                float dist = fmaxf(sqrtf(d2), 1e-15f);
                float t3 = 1.7320508075688772f * dist;
                o[r] = (1.0f + t3) * __expf(-t3);
            }
            __builtin_nontemporal_store(o, (f32x4*)&rowp[j * 16]);
        }
    }
}

extern "C" void kernel_launch(void* const* d_in, const int* in_sizes, int n_in,
                              void* d_out, int out_size, void* d_ws, size_t ws_size,
                              hipStream_t stream) {
    const float* x1 = (const float*)d_in[0];
    const float* x2 = (const float*)d_in[1];
    const float* ls = (const float*)d_in[2];
    float* out = (float*)d_out;

    // workspace: adj[256]f32 | sq1[8192]f32 | sq2[8192]f32 | y1 fp16 4MB | y2 fp16 4MB
    char* ws = (char*)d_ws;
    float* adj = (float*)ws;
    float* sq1 = (float*)(ws + 1024);
    float* sq2 = (float*)(ws + 1024 + 32768);
    _Float16* y1 = (_Float16*)(ws + 66560);
    _Float16* y2 = (_Float16*)(ws + 66560 + 4194304);

    hipMemsetAsync(adj, 0, 256 * sizeof(float), stream);
    colmean_kernel<<<N1 / 16, 256, 0, stream>>>(x1, adj);
    quant_kernel<<<(N1 + N2) / 4, 256, 0, stream>>>(x1, x2, adj, ls, y1, y2, sq1, sq2);
    matern_gemm<<<dim3(N1 / TILE, N2 / TILE), 256, 0, stream>>>(y1, y2, sq1, sq2, out);
}